// Round 6
// baseline (1403.913 us; speedup 1.0000x reference)
//
#include <hip/hip_runtime.h>
#include <math.h>

#define TB   64
#define TT   255
#define TIN  32
#define NH   256
#define NE   128
#define NK   255
#define NPAD 127

typedef __attribute__((ext_vector_type(8))) short short8;
typedef __attribute__((ext_vector_type(16))) float float16v;

// ---- workspace layout (byte offsets) ----
// wp1: [255][nt8][kg2][p2][64][8] bf16 = 8,355,840 B   (aliased by z after conv1)
// wp2: [255][hcg8][nt4][kg2][p2][64][8] bf16 = 33,423,360 B
// hf : [64][256 t][256 ch] f32 = 16,777,216 B          (aliased by hmid after conv2)
// z  : [64][128 e][255 t] f32 = 8,355,840 B            (aliases wp1)
#define WSB_WP1  0u
#define WSB_Z    0u
#define WSB_WP2  8388608u
#define WSB_H    41811968u
#define WSB_HMID 41811968u
#define WSB_BN   58589184u   // 4 x 256 f32: sum1/sum2/sc/sh

// ---- output layout (float offsets) ----
#define O_AMP   0u
#define O_PHASE 8128u
#define O_FREQ  16320u
#define O_OFF   24448u

static __device__ __forceinline__ unsigned short f2bf(float f) {
  unsigned int u = __float_as_uint(f);
  unsigned int r = (u + 0x7FFFu + ((u >> 16) & 1u)) >> 16;
  return (unsigned short)r;
}
static __device__ __forceinline__ float bf2f(unsigned short s) {
  return __uint_as_float(((unsigned int)s) << 16);
}
static __device__ __forceinline__ short8 as_s8(uint4 v) {
  union { uint4 u; short8 s; } c; c.u = v; return c.s;
}

// ---------------- small init kernels ----------------
__global__ __launch_bounds__(256) void bn_zero_k(float* __restrict__ bn) {
  bn[threadIdx.x] = 0.f;
  bn[256 + threadIdx.x] = 0.f;
}

__global__ __launch_bounds__(1024) void z_init_k(const float* __restrict__ b2,
                                                 float* __restrict__ z) {
  int idx = blockIdx.x * 1024 + threadIdx.x;   // 2040*1024 == 64*128*255
  int e = (idx / TT) % NE;
  z[idx] = b2[e];
}

// ---------------- weight packing for 32x32x16 MFMA (hi/lo split) --------------
// wp1 uint idx = (((kk*8 + nt)*2 + kg)*2 + p)*256 + lane*4 + jp
// value: w1[ch = nt*32 + (lane&31)][i = kg*16 + (lane>>5)*8 + jp*2 (+1)][kk]
__global__ __launch_bounds__(256) void pack1_k(const float* __restrict__ w1,
                                               unsigned int* __restrict__ wp1u) {
  __shared__ float tile[32][32][9];   // [ch_l][i_l][kl]
  const int nt = blockIdx.x, kc = blockIdx.y;
  const int kk0 = kc * 8, cnt = min(8, NK - kk0);
  const int tid = threadIdx.x;
  for (int idx = tid; idx < 1024 * 8; idx += 256) {
    int row = idx >> 3, kl = idx & 7;
    if (kl < cnt) {
      int ch_l = row >> 5, i_l = row & 31;
      tile[ch_l][i_l][kl] = w1[(size_t)((nt * 32 + ch_l) * TIN + i_l) * NK + kk0 + kl];
    }
  }
  __syncthreads();
  const int lane = tid >> 2, jp = tid & 3;
  const int l31 = lane & 31, half = lane >> 5;
  for (int kl = 0; kl < cnt; ++kl) {
#pragma unroll
    for (int kg = 0; kg < 2; ++kg) {
      int i0 = kg * 16 + half * 8 + jp * 2;
      float v0 = tile[l31][i0][kl], v1 = tile[l31][i0 + 1][kl];
      unsigned short h0 = f2bf(v0), h1 = f2bf(v1);
      unsigned short l0 = f2bf(v0 - bf2f(h0)), l1 = f2bf(v1 - bf2f(h1));
      size_t base = ((((size_t)(kk0 + kl) * 8 + nt) * 2 + kg) * 2) * 256 + tid;
      wp1u[base] = (unsigned int)h0 | ((unsigned int)h1 << 16);
      wp1u[base + 256] = (unsigned int)l0 | ((unsigned int)l1 << 16);
    }
  }
}

// wp2 uint idx = ((((kk*8 + hcg)*4 + nt)*2 + kg)*2 + p)*256 + lane*4 + jp
// value: w2[e = nt*32 + (lane&31)][h = hcg*32 + kg*16 + (lane>>5)*8 + jp*2 (+1)][kk]
__global__ __launch_bounds__(256) void pack2_k(const float* __restrict__ w2,
                                               unsigned int* __restrict__ wp2u) {
  __shared__ float tile[32][32][9];   // [e_l][h_l][kl]
  const int hcg = blockIdx.x >> 2, nt = blockIdx.x & 3, kc = blockIdx.y;
  const int kk0 = kc * 8, cnt = min(8, NK - kk0);
  const int tid = threadIdx.x;
  for (int idx = tid; idx < 1024 * 8; idx += 256) {
    int row = idx >> 3, kl = idx & 7;
    if (kl < cnt) {
      int e_l = row >> 5, h_l = row & 31;
      tile[e_l][h_l][kl] = w2[(size_t)((nt * 32 + e_l) * NH + hcg * 32 + h_l) * NK + kk0 + kl];
    }
  }
  __syncthreads();
  const int lane = tid >> 2, jp = tid & 3;
  const int l31 = lane & 31, half = lane >> 5;
  for (int kl = 0; kl < cnt; ++kl) {
#pragma unroll
    for (int kg = 0; kg < 2; ++kg) {
      int h0i = kg * 16 + half * 8 + jp * 2;
      float v0 = tile[l31][h0i][kl], v1 = tile[l31][h0i + 1][kl];
      unsigned short h0 = f2bf(v0), h1 = f2bf(v1);
      unsigned short l0 = f2bf(v0 - bf2f(h0)), l1 = f2bf(v1 - bf2f(h1));
      size_t base = (((((size_t)(kk0 + kl) * 8 + hcg) * 4 + nt) * 2 + kg) * 2) * 256 + tid;
      wp2u[base] = (unsigned int)h0 | ((unsigned int)h1 << 16);
      wp2u[base + 256] = (unsigned int)l0 | ((unsigned int)l1 << 16);
    }
  }
}

// ---------------- conv1 MFMA (32x32x16, split-bf16 3-term, kg-split) ----------
// grid (16 = 4 th x 4 chg, 64 b), 256 thr = 4 waves = eg2 x kg2.
// Block tile 64t x 64ch; wave 64t x 32ch x 16i. A rows 318, 40 KB LDS.
// BN stats fused into epilogue.
#define C1_ROWS 318
__global__ __launch_bounds__(256, 4) void conv1_mfma(
    const float* __restrict__ s, const unsigned int* __restrict__ wp1u,
    const float* __restrict__ b1v, float* __restrict__ hf, float* __restrict__ bn) {
  __shared__ __align__(16) unsigned short Alds[C1_ROWS * 64];   // 40704 B
  const int th = blockIdx.x & 3, chg = blockIdx.x >> 2, b = blockIdx.y;
  const int tid = threadIdx.x, lane = tid & 63, wv = tid >> 6;
  const int kg = wv & 1, eg = wv >> 1;
  const int l31 = lane & 31, half = lane >> 5;
  const int bi = kg * 2 + half;
  const int nt = chg * 2 + eg;
  unsigned int* Au = (unsigned int*)Alds;

  // stage A: rows r -> t = th*64 + r - 127; [32 i hi][32 i lo], XOR-swizzled
  for (int idx = tid; idx < C1_ROWS * 16; idx += 256) {
    int r = idx >> 4, p = idx & 15;
    int t = th * 64 + r - NPAD;
    float v0 = 0.f, v1 = 0.f;
    if (t >= 0 && t < TT) {
      const float* sp = &s[(size_t)(b * TT + t) * TIN + p * 2];
      v0 = sp[0]; v1 = sp[1];
    }
    unsigned short h0 = f2bf(v0), h1 = f2bf(v1);
    unsigned short l0 = f2bf(v0 - bf2f(h0)), l1 = f2bf(v1 - bf2f(h1));
    int sw = r & 7;
    Au[r * 32 + ((((p >> 2) ^ sw) << 2) | (p & 3))] = (unsigned int)h0 | ((unsigned int)h1 << 16);
    Au[r * 32 + (((((p >> 2) + 4) ^ sw) << 2) | (p & 3))] = (unsigned int)l0 | ((unsigned int)l1 << 16);
  }

#define LOADB1(buf, KK) do {                                                      \
    const uint4* _b = (const uint4*)wp1u +                                        \
        ((((size_t)(KK) * 8 + nt) * 2 + kg) * 2) * 64;                            \
    buf[0] = _b[lane];  buf[1] = _b[64 + lane];                                   \
  } while (0)

#define MSTEP1(KK, buf) do {                                                      \
    short8 bh = as_s8(buf[0]), bl = as_s8(buf[1]);                                \
    _Pragma("unroll")                                                             \
    for (int mi = 0; mi < 2; ++mi) {                                              \
      const int row = mi * 32 + l31 + (KK);                                       \
      const int sw = row & 7;                                                     \
      short8 ah = *(const short8*)&Alds[row * 64 + ((bi ^ sw) << 3)];             \
      short8 al = *(const short8*)&Alds[row * 64 + (((bi + 4) ^ sw) << 3)];       \
      acc[mi] = __builtin_amdgcn_mfma_f32_32x32x16_bf16(ah, bh, acc[mi], 0, 0, 0);\
      acc[mi] = __builtin_amdgcn_mfma_f32_32x32x16_bf16(ah, bl, acc[mi], 0, 0, 0);\
      acc[mi] = __builtin_amdgcn_mfma_f32_32x32x16_bf16(al, bh, acc[mi], 0, 0, 0);\
    }                                                                             \
  } while (0)

  uint4 b0[2], b1x[2];
  LOADB1(b0, 0);
  __syncthreads();

  float16v acc[2];
#pragma unroll
  for (int mi = 0; mi < 2; ++mi) acc[mi] = (float16v)(0.f);

  for (int kp = 0; kp < 127; ++kp) {
    const int kk = kp * 2;
    LOADB1(b1x, kk + 1);
    MSTEP1(kk, b0);
    LOADB1(b0, kk + 2);
    MSTEP1(kk + 1, b1x);
  }
  MSTEP1(254, b0);

  // kg reduction via LDS (A region dead), then epilogue + fused BN stats
  __syncthreads();
  float* R = (float*)Alds;
  if (kg == 1) {
#pragma unroll
    for (int mi = 0; mi < 2; ++mi)
#pragma unroll
      for (int r = 0; r < 16; ++r)
        R[((eg * 2 + mi) * 16 + r) * 64 + lane] = acc[mi][r];
  }
  __syncthreads();
  if (kg == 0) {
    const int ch = nt * 32 + l31;
    const float bias = b1v[ch];
    float s1 = 0.f, s2 = 0.f;
#pragma unroll
    for (int mi = 0; mi < 2; ++mi) {
#pragma unroll
      for (int r = 0; r < 16; ++r) {
        float v = acc[mi][r] + R[((eg * 2 + mi) * 16 + r) * 64 + lane] + bias;
        v = fmaxf(v, 0.f);
        int t = th * 64 + mi * 32 + (r & 3) + 8 * (r >> 2) + 4 * half;
        if (t < TT) {
          hf[(size_t)(b * 256 + t) * NH + ch] = v;
          s1 += v; s2 += v * v;
        }
      }
    }
    s1 += __shfl_xor(s1, 32);
    s2 += __shfl_xor(s2, 32);
    if (half == 0) {
      atomicAdd(&bn[ch], s1);
      atomicAdd(&bn[256 + ch], s2);
    }
  }
#undef LOADB1
#undef MSTEP1
}

__global__ __launch_bounds__(256) void bn_final_k(const float* __restrict__ gamma,
                                                  const float* __restrict__ beta,
                                                  float* __restrict__ bn) {
  const int h = threadIdx.x;
  const float inv = 1.0f / (TB * TT);
  float m = bn[h] * inv;
  float var = bn[256 + h] * inv - m * m;
  float sc = gamma[h] / sqrtf(var + 1e-5f);
  bn[512 + h] = sc;
  bn[768 + h] = beta[h] - m * sc;
}

// ---------------- conv2 MFMA (32x32x16, split-bf16 3-term, kg-split) ----------
// grid (16 = 4 th x 4 hs, 64 b), 256 thr = 4 waves = eg2 x kg2.
// Block tile 64t x 128e, 2 h-chunks of 32 (kg halves each). A rows 318, 40 KB.
#define C2_ROWS 318
__global__ __launch_bounds__(256, 4) void conv2_mfma(
    const float* __restrict__ hf, const unsigned int* __restrict__ wp2u,
    const float* __restrict__ bn, float* __restrict__ z) {
  __shared__ __align__(16) unsigned short Alds[C2_ROWS * 64];   // 40704 B
  const int th = blockIdx.x & 3, hs = blockIdx.x >> 2, b = blockIdx.y;
  const int tid = threadIdx.x, lane = tid & 63, wv = tid >> 6;
  const int kg = wv & 1, eg = wv >> 1;
  const int l31 = lane & 31, half = lane >> 5;
  const int bi = kg * 2 + half;
  unsigned int* Au = (unsigned int*)Alds;

#define LOADB2(buf, KK, HCG) do {                                                 \
    const uint4* _b = (const uint4*)wp2u +                                        \
        (((((size_t)(KK) * 8 + (HCG)) * 4 + eg * 2) * 2 + kg) * 2) * 64;          \
    buf[0] = _b[lane];        buf[1] = _b[64 + lane];                             \
    buf[2] = _b[256 + lane];  buf[3] = _b[320 + lane];                            \
  } while (0)

#define MSTEP2(KK, buf) do {                                                      \
    short8 bh0 = as_s8(buf[0]), bl0 = as_s8(buf[1]);                              \
    short8 bh1 = as_s8(buf[2]), bl1 = as_s8(buf[3]);                              \
    _Pragma("unroll")                                                             \
    for (int mi = 0; mi < 2; ++mi) {                                              \
      const int row = mi * 32 + l31 + (KK);                                       \
      const int sw = row & 7;                                                     \
      short8 ah = *(const short8*)&Alds[row * 64 + ((bi ^ sw) << 3)];             \
      short8 al = *(const short8*)&Alds[row * 64 + (((bi + 4) ^ sw) << 3)];       \
      acc[mi][0] = __builtin_amdgcn_mfma_f32_32x32x16_bf16(ah, bh0, acc[mi][0], 0, 0, 0); \
      acc[mi][0] = __builtin_amdgcn_mfma_f32_32x32x16_bf16(ah, bl0, acc[mi][0], 0, 0, 0); \
      acc[mi][0] = __builtin_amdgcn_mfma_f32_32x32x16_bf16(al, bh0, acc[mi][0], 0, 0, 0); \
      acc[mi][1] = __builtin_amdgcn_mfma_f32_32x32x16_bf16(ah, bh1, acc[mi][1], 0, 0, 0); \
      acc[mi][1] = __builtin_amdgcn_mfma_f32_32x32x16_bf16(ah, bl1, acc[mi][1], 0, 0, 0); \
      acc[mi][1] = __builtin_amdgcn_mfma_f32_32x32x16_bf16(al, bh1, acc[mi][1], 0, 0, 0); \
    }                                                                             \
  } while (0)

  float16v acc[2][2];
#pragma unroll
  for (int mi = 0; mi < 2; ++mi)
#pragma unroll
    for (int ni = 0; ni < 2; ++ni) acc[mi][ni] = (float16v)(0.f);

  uint4 b0[4], b1x[4];

  for (int hc = 0; hc < 2; ++hc) {
    const int hcg = hs * 2 + hc;
    __syncthreads();   // all reads of Alds from previous chunk done
    for (int idx = tid; idx < C2_ROWS * 16; idx += 256) {
      int r = idx >> 4, p = idx & 15;
      int t = th * 64 + r - NPAD;
      float v0 = 0.f, v1 = 0.f;
      int h0c = hcg * 32 + p * 2;
      if (t >= 0 && t < TT) {
        const float* hp = &hf[(size_t)(b * 256 + t) * NH + h0c];
        v0 = hp[0] * bn[512 + h0c] + bn[768 + h0c];
        v1 = hp[1] * bn[512 + h0c + 1] + bn[768 + h0c + 1];
      }
      unsigned short h0 = f2bf(v0), h1 = f2bf(v1);
      unsigned short l0 = f2bf(v0 - bf2f(h0)), l1 = f2bf(v1 - bf2f(h1));
      int sw = r & 7;
      Au[r * 32 + ((((p >> 2) ^ sw) << 2) | (p & 3))] = (unsigned int)h0 | ((unsigned int)h1 << 16);
      Au[r * 32 + (((((p >> 2) + 4) ^ sw) << 2) | (p & 3))] = (unsigned int)l0 | ((unsigned int)l1 << 16);
    }
    if (hc == 0) LOADB2(b0, 0, hcg);
    __syncthreads();

    for (int kp = 0; kp < 127; ++kp) {
      const int kk = kp * 2;
      LOADB2(b1x, kk + 1, hcg);
      MSTEP2(kk, b0);
      LOADB2(b0, kk + 2, hcg);
      MSTEP2(kk + 1, b1x);
    }
    MSTEP2(254, b0);
    if (hc == 0) LOADB2(b0, 0, hcg + 1);   // cross-chunk prefetch
  }

#pragma unroll
  for (int mi = 0; mi < 2; ++mi) {
#pragma unroll
    for (int ni = 0; ni < 2; ++ni) {
      int e = eg * 64 + ni * 32 + l31;
#pragma unroll
      for (int r = 0; r < 16; ++r) {
        int t = th * 64 + mi * 32 + (r & 3) + 8 * (r >> 2) + 4 * half;
        if (t < TT) atomicAdd(&z[(size_t)(b * NE + e) * TT + t], acc[mi][ni][r]);
      }
    }
  }
#undef LOADB2
#undef MSTEP2
}

// ---------------- MLP layer 1 (fp32) ----------------
__global__ __launch_bounds__(256) void mlp1_k(const float* __restrict__ z,
                                              const float* __restrict__ pw1,
                                              const float* __restrict__ pb1,
                                              float* __restrict__ hmid) {
  const int TC = 128;
  __shared__ float zl[TC * 68];
  __shared__ float pl[TC * 68];
  const int c = blockIdx.y, h0 = blockIdx.x * 64, tid = threadIdx.x;
  const int h4 = tid & 15, b4 = tid >> 4;
  float acc[4][4];
#pragma unroll
  for (int a = 0; a < 4; ++a)
#pragma unroll
    for (int bb = 0; bb < 4; ++bb) acc[a][bb] = 0.f;
  for (int t0 = 0; t0 < TT; t0 += TC) {
    const int tc = min(TC, TT - t0);
    __syncthreads();
    for (int idx = tid; idx < 64 * tc; idx += 256) {
      int r = idx / tc, t = idx - r * tc;
      zl[t * 68 + r] = z[(size_t)(r * NE + c) * TT + t0 + t];
      pl[t * 68 + r] = pw1[(size_t)(c * NH + h0 + r) * TT + t0 + t];
    }
    __syncthreads();
    for (int t = 0; t < tc; ++t) {
      float4 zv = *(const float4*)&zl[t * 68 + b4 * 4];
      float4 pv = *(const float4*)&pl[t * 68 + h4 * 4];
      float zz[4] = {zv.x, zv.y, zv.z, zv.w};
      float pp[4] = {pv.x, pv.y, pv.z, pv.w};
#pragma unroll
      for (int a = 0; a < 4; ++a)
#pragma unroll
        for (int bb = 0; bb < 4; ++bb) acc[a][bb] = fmaf(pp[a], zz[bb], acc[a][bb]);
    }
  }
#pragma unroll
  for (int a = 0; a < 4; ++a) {
    int hh = h0 + h4 * 4 + a;
    float bias = pb1[c * NH + hh];
#pragma unroll
    for (int bb = 0; bb < 4; ++bb) {
      int bidx = b4 * 4 + bb;
      float v = acc[a][bb] + bias;
      hmid[(size_t)(bidx * NE + c) * NH + hh] = fmaxf(v, 0.f);
    }
  }
}

// ---------------- MLP layer 2 + atan2 ----------------
__global__ __launch_bounds__(256) void mlp2_k(const float* __restrict__ hmid,
                                              const float* __restrict__ pw2,
                                              const float* __restrict__ pb2,
                                              float* __restrict__ out) {
  const int tid = threadIdx.x, lane = tid & 63, wv = tid >> 6;
  const int p = blockIdx.x * 4 + wv;
  const int b = p >> 7, c = p & 127;
  const float4 hv = *(const float4*)&hmid[(size_t)(b * NE + c) * NH + lane * 4];
  const float4 p0 = *(const float4*)&pw2[(size_t)(c * 2 + 0) * NH + lane * 4];
  const float4 p1 = *(const float4*)&pw2[(size_t)(c * 2 + 1) * NH + lane * 4];
  float s0 = hv.x * p0.x + hv.y * p0.y + hv.z * p0.z + hv.w * p0.w;
  float s1 = hv.x * p1.x + hv.y * p1.y + hv.z * p1.z + hv.w * p1.w;
#pragma unroll
  for (int off = 32; off; off >>= 1) {
    s0 += __shfl_down(s0, off);
    s1 += __shfl_down(s1, off);
  }
  if (lane == 0) {
    float a0 = s0 + pb2[c * 2 + 0];
    float a1 = s1 + pb2[c * 2 + 1];
    out[O_PHASE + b * NE + c] = atan2f(a1, a0);
  }
}

// ---------------- amplitude (Parseval) + constant frequency ----------------
__global__ __launch_bounds__(256) void amp_k(const float* __restrict__ z,
                                             float* __restrict__ out) {
  const int tid = threadIdx.x, lane = tid & 63, wv = tid >> 6;
  const int b = blockIdx.x, c = blockIdx.y * 4 + wv;
  const float* row = z + (size_t)(b * NE + c) * TT;
  float s1 = 0.f, s2 = 0.f;
  for (int idx = lane; idx < TT; idx += 64) {
    float v = row[idx];
    s1 += v; s2 += v * v;
  }
#pragma unroll
  for (int off = 32; off; off >>= 1) {
    s1 += __shfl_down(s1, off);
    s2 += __shfl_down(s2, off);
  }
  if (lane == 0 && c >= 1) {
    float P = 0.5f * (255.f * s2 + s1 * s1);
    out[O_AMP + b * 127 + (c - 1)] = 2.f * sqrtf(P) / 255.f;
    out[O_FREQ + b * 127 + (c - 1)] = (float)c / 255.f;
  }
}

// ---------------- offset: real rfft spectrum of channel 0 ----------------
__global__ __launch_bounds__(128) void offset_k(const float* __restrict__ z,
                                                float* __restrict__ out) {
  __shared__ float zr[TT];
  __shared__ float ct[TT];
  const int b = blockIdx.x, tid = threadIdx.x;
  for (int idx = tid; idx < TT; idx += 128) {
    zr[idx] = z[(size_t)(b * NE + 0) * TT + idx];
    ct[idx] = cosf(6.283185307179586f * (float)idx / 255.f);
  }
  __syncthreads();
  const int f = tid;
  float s = 0.f;
  int m = 0;
  for (int t = 0; t < TT; ++t) {
    s += zr[t] * ct[m];
    m += f; if (m >= TT) m -= TT;
  }
  out[O_OFF + b * NE + f] = s / 255.f;
}

extern "C" void kernel_launch(void* const* d_in, const int* in_sizes, int n_in,
                              void* d_out, int out_size, void* d_ws, size_t ws_size,
                              hipStream_t stream) {
  (void)in_sizes; (void)n_in; (void)out_size; (void)ws_size;
  const float* s       = (const float*)d_in[0];
  const float* conv1_w = (const float*)d_in[1];
  const float* conv1_b = (const float*)d_in[2];
  const float* bn_g    = (const float*)d_in[3];
  const float* bn_b    = (const float*)d_in[4];
  const float* conv2_w = (const float*)d_in[5];
  const float* conv2_b = (const float*)d_in[6];
  const float* pw1     = (const float*)d_in[7];
  const float* pb1     = (const float*)d_in[8];
  const float* pw2     = (const float*)d_in[9];
  const float* pb2     = (const float*)d_in[10];
  float* out = (float*)d_out;
  char* ws   = (char*)d_ws;

  unsigned int* wp1u = (unsigned int*)(ws + WSB_WP1);
  unsigned int* wp2u = (unsigned int*)(ws + WSB_WP2);
  float* hf   = (float*)(ws + WSB_H);
  float* z    = (float*)(ws + WSB_Z);      // aliases wp1 (dead after conv1)
  float* bn   = (float*)(ws + WSB_BN);
  float* hmid = (float*)(ws + WSB_HMID);   // aliases hf (dead after conv2)

  bn_zero_k<<<1, 256, 0, stream>>>(bn);
  pack1_k<<<dim3(8, 32), 256, 0, stream>>>(conv1_w, wp1u);
  pack2_k<<<dim3(32, 32), 256, 0, stream>>>(conv2_w, wp2u);

  conv1_mfma<<<dim3(16, TB), 256, 0, stream>>>(s, wp1u, conv1_b, hf, bn);
  bn_final_k<<<1, 256, 0, stream>>>(bn_g, bn_b, bn);

  z_init_k<<<2040, 1024, 0, stream>>>(conv2_b, z);   // overwrites wp1 region
  conv2_mfma<<<dim3(16, TB), 256, 0, stream>>>(hf, wp2u, bn, z);

  mlp1_k<<<dim3(4, NE), 256, 0, stream>>>(z, pw1, pb1, hmid);
  mlp2_k<<<TB * NE / 4, 256, 0, stream>>>(hmid, pw2, pb2, out);
  amp_k<<<dim3(TB, 32), 256, 0, stream>>>(z, out);
  offset_k<<<TB, 128, 0, stream>>>(z, out);
}

// Round 7
// 1028.603 us; speedup vs baseline: 1.3649x; 1.3649x over previous
//
#include <hip/hip_runtime.h>
#include <math.h>

#define TB   64
#define TT   255
#define TIN  32
#define NH   256
#define NE   128
#define NK   255
#define NPAD 127

typedef __attribute__((ext_vector_type(8))) short short8;
typedef __attribute__((ext_vector_type(4))) float float4v;

// ---- workspace layout (byte offsets) ----
#define WSB_WP1  0u
#define WSB_Z    0u
#define WSB_WP2  8388608u
#define WSB_H    41811968u
#define WSB_HMID 41811968u
#define WSB_BN   58589184u   // 4 x 256 f32: sum1/sum2/sc/sh

// ---- output layout (float offsets) ----
#define O_AMP   0u
#define O_PHASE 8128u
#define O_FREQ  16320u
#define O_OFF   24448u

static __device__ __forceinline__ unsigned short f2bf(float f) {
  unsigned int u = __float_as_uint(f);
  unsigned int r = (u + 0x7FFFu + ((u >> 16) & 1u)) >> 16;
  return (unsigned short)r;
}
static __device__ __forceinline__ float bf2f(unsigned short s) {
  return __uint_as_float(((unsigned int)s) << 16);
}
static __device__ __forceinline__ short8 as_s8(uint4 v) {
  union { uint4 u; short8 s; } c; c.u = v; return c.s;
}

// ---------------- small init kernels ----------------
__global__ __launch_bounds__(256) void bn_zero_k(float* __restrict__ bn) {
  bn[threadIdx.x] = 0.f;
  bn[256 + threadIdx.x] = 0.f;
}

__global__ __launch_bounds__(1024) void z_init_k(const float* __restrict__ b2,
                                                 float* __restrict__ z) {
  int idx = blockIdx.x * 1024 + threadIdx.x;   // 2040*1024 == 64*128*255
  int e = (idx / TT) % NE;
  z[idx] = b2[e];
}

// ---------------- weight packing (hi/lo split) ----------------
// wp1[kk][et(16)][p(2)][lane][j]: split_p( w1[e=et*16+(lane&15)][i=(lane>>4)*8+j][kk] )
__global__ __launch_bounds__(256) void pack1_k(const float* __restrict__ w1,
                                               unsigned int* __restrict__ wp1u) {
  __shared__ float tile[512][33];
  const int et = blockIdx.x, kc = blockIdx.y;
  const int kk0 = kc * 32, cnt = min(32, NK - kk0);
  const int tid = threadIdx.x;
  for (int idx = tid; idx < 512 * 32; idx += 256) {
    int row = idx >> 5, kl = idx & 31;
    if (kl < cnt) {
      int e_l = row >> 5, i_l = row & 31;
      tile[row][kl] = w1[(size_t)((et * 16 + e_l) * TIN + i_l) * NK + kk0 + kl];
    }
  }
  __syncthreads();
  const int lane = tid >> 2, jp = (tid & 3) * 2;
  const int row0 = (lane & 15) * 32 + (lane >> 4) * 8 + jp;
  for (int kl = 0; kl < cnt; ++kl) {
    float w0 = tile[row0][kl], w1v = tile[row0 + 1][kl];
    unsigned short h0 = f2bf(w0), h1 = f2bf(w1v);
    unsigned short l0 = f2bf(w0 - bf2f(h0)), l1 = f2bf(w1v - bf2f(h1));
    size_t base = (size_t)(kk0 + kl) * 8192 + et * 512 + tid;
    wp1u[base] = (unsigned int)h0 | ((unsigned int)h1 << 16);
    wp1u[base + 256] = (unsigned int)l0 | ((unsigned int)l1 << 16);
  }
}

// wp2[kk][hcg(8)][et(8)][p(2)][lane][j]: split_p( w2[e=et*16+(lane&15)][h=hcg*32+(lane>>4)*8+j][kk] )
__global__ __launch_bounds__(256) void pack2_k(const float* __restrict__ w2,
                                               unsigned int* __restrict__ wp2u) {
  __shared__ float tile[512][33];
  const int hcg = blockIdx.x >> 3, et = blockIdx.x & 7, kc = blockIdx.y;
  const int kk0 = kc * 32, cnt = min(32, NK - kk0);
  const int tid = threadIdx.x;
  for (int idx = tid; idx < 512 * 32; idx += 256) {
    int row = idx >> 5, kl = idx & 31;
    if (kl < cnt) {
      int e_l = row >> 5, h_l = row & 31;
      tile[row][kl] = w2[(size_t)((et * 16 + e_l) * NH + hcg * 32 + h_l) * NK + kk0 + kl];
    }
  }
  __syncthreads();
  const int lane = tid >> 2, jp = (tid & 3) * 2;
  const int row0 = (lane & 15) * 32 + (lane >> 4) * 8 + jp;
  for (int kl = 0; kl < cnt; ++kl) {
    float w0 = tile[row0][kl], w1v = tile[row0 + 1][kl];
    unsigned short h0 = f2bf(w0), h1 = f2bf(w1v);
    unsigned short l0 = f2bf(w0 - bf2f(h0)), l1 = f2bf(w1v - bf2f(h1));
    size_t base = (size_t)(kk0 + kl) * 32768 + hcg * 4096 + et * 512 + tid;
    wp2u[base] = (unsigned int)h0 | ((unsigned int)h1 << 16);
    wp2u[base + 256] = (unsigned int)l0 | ((unsigned int)l1 << 16);
  }
}

// ---------------- conv1 MFMA (split-bf16 3-term, register-streamed B) ---------
// grid (8 = 2 th x 4 chg, 64 b), 256 thr. Block: 128t x 64ch.
// Waves: 2tg x 2eg, each 64t x 32ch (mi=4, ni=2). LDS 48 KB. Fused BN stats.
#define C1_ROWS 384
__global__ __launch_bounds__(256, 2) void conv1_mfma(
    const float* __restrict__ s, const unsigned int* __restrict__ wp1u,
    const float* __restrict__ b1v, float* __restrict__ hf, float* __restrict__ bn) {
  __shared__ __align__(16) unsigned short Alds[C1_ROWS * 64];   // 49152 B
  const int th = blockIdx.x & 1, chg = blockIdx.x >> 1, b = blockIdx.y;
  const int tid = threadIdx.x, lane = tid & 63, wv = tid >> 6;
  const int quad = lane >> 4, l15 = lane & 15;
  const int tg = wv & 1, eg = wv >> 1;
  unsigned int* Au = (unsigned int*)Alds;

  for (int idx = tid; idx < C1_ROWS * 16; idx += 256) {
    int r = idx >> 4, p = idx & 15;
    int t = th * 128 + r - NPAD;
    float v0 = 0.f, v1 = 0.f;
    if (t >= 0 && t < TT) {
      const float* sp = &s[(size_t)(b * TT + t) * TIN + p * 2];
      v0 = sp[0]; v1 = sp[1];
    }
    unsigned short h0 = f2bf(v0), h1 = f2bf(v1);
    unsigned short l0 = f2bf(v0 - bf2f(h0)), l1 = f2bf(v1 - bf2f(h1));
    int sw = r & 7;
    Au[r * 32 + ((((p >> 2) ^ sw) << 2) | (p & 3))] = (unsigned int)h0 | ((unsigned int)h1 << 16);
    Au[r * 32 + (((((p >> 2) + 4) ^ sw) << 2) | (p & 3))] = (unsigned int)l0 | ((unsigned int)l1 << 16);
  }

#define LOADB1(buf, KK) do {                                                      \
    const uint4* _b = (const uint4*)(wp1u + (size_t)(KK) * 8192u) +               \
                      (chg * 4 + eg * 2) * 128;                                   \
    buf[0] = _b[lane];          buf[1] = _b[64 + lane];                           \
    buf[2] = _b[128 + lane];    buf[3] = _b[192 + lane];                          \
  } while (0)

#define MSTEP1(KK, buf) do {                                                      \
    short8 bh0 = as_s8(buf[0]), bl0 = as_s8(buf[1]);                              \
    short8 bh1 = as_s8(buf[2]), bl1 = as_s8(buf[3]);                              \
    _Pragma("unroll")                                                             \
    for (int mi = 0; mi < 4; ++mi) {                                              \
      const int row = tg * 64 + mi * 16 + l15 + (KK);                             \
      const int sw = row & 7;                                                     \
      short8 ah = *(const short8*)&Alds[row * 64 + ((quad ^ sw) << 3)];           \
      short8 al = *(const short8*)&Alds[row * 64 + (((quad ^ 4) ^ sw) << 3)];     \
      acc[mi][0] = __builtin_amdgcn_mfma_f32_16x16x32_bf16(ah, bh0, acc[mi][0], 0, 0, 0); \
      acc[mi][0] = __builtin_amdgcn_mfma_f32_16x16x32_bf16(ah, bl0, acc[mi][0], 0, 0, 0); \
      acc[mi][0] = __builtin_amdgcn_mfma_f32_16x16x32_bf16(al, bh0, acc[mi][0], 0, 0, 0); \
      acc[mi][1] = __builtin_amdgcn_mfma_f32_16x16x32_bf16(ah, bh1, acc[mi][1], 0, 0, 0); \
      acc[mi][1] = __builtin_amdgcn_mfma_f32_16x16x32_bf16(ah, bl1, acc[mi][1], 0, 0, 0); \
      acc[mi][1] = __builtin_amdgcn_mfma_f32_16x16x32_bf16(al, bh1, acc[mi][1], 0, 0, 0); \
    }                                                                             \
  } while (0)

  uint4 b0[4], b1x[4];
  LOADB1(b0, 0);
  __syncthreads();

  float4v acc[4][2];
#pragma unroll
  for (int mi = 0; mi < 4; ++mi)
#pragma unroll
    for (int ni = 0; ni < 2; ++ni) acc[mi][ni] = (float4v)(0.f);

  for (int kp = 0; kp < 127; ++kp) {
    const int kk = kp * 2;
    LOADB1(b1x, kk + 1);
    MSTEP1(kk, b0);
    LOADB1(b0, kk + 2);
    MSTEP1(kk + 1, b1x);
  }
  MSTEP1(254, b0);

  // epilogue + fused BN partial sums (sum over this wave's t-range)
  float s1[2] = {0.f, 0.f}, s2[2] = {0.f, 0.f};
#pragma unroll
  for (int mi = 0; mi < 4; ++mi) {
#pragma unroll
    for (int ni = 0; ni < 2; ++ni) {
      int ch = chg * 64 + (eg * 2 + ni) * 16 + l15;
      float bias = b1v[ch];
#pragma unroll
      for (int r = 0; r < 4; ++r) {
        int t = th * 128 + tg * 64 + mi * 16 + quad * 4 + r;
        if (t < TT) {
          float v = fmaxf(acc[mi][ni][r] + bias, 0.f);
          hf[(size_t)(b * 256 + t) * NH + ch] = v;
          s1[ni] += v; s2[ni] += v * v;
        }
      }
    }
  }
#pragma unroll
  for (int ni = 0; ni < 2; ++ni) {
    s1[ni] += __shfl_xor(s1[ni], 16);
    s1[ni] += __shfl_xor(s1[ni], 32);
    s2[ni] += __shfl_xor(s2[ni], 16);
    s2[ni] += __shfl_xor(s2[ni], 32);
    if (quad == 0) {
      int ch = chg * 64 + (eg * 2 + ni) * 16 + l15;
      atomicAdd(&bn[ch], s1[ni]);
      atomicAdd(&bn[256 + ch], s2[ni]);
    }
  }
#undef LOADB1
#undef MSTEP1
}

__global__ __launch_bounds__(256) void bn_final_k(const float* __restrict__ gamma,
                                                  const float* __restrict__ beta,
                                                  float* __restrict__ bn) {
  const int h = threadIdx.x;
  const float inv = 1.0f / (TB * TT);
  float m = bn[h] * inv;
  float var = bn[256 + h] * inv - m * m;
  float sc = gamma[h] / sqrtf(var + 1e-5f);
  bn[512 + h] = sc;
  bn[768 + h] = beta[h] - m * sc;
}

// ---------------- conv2 MFMA (split-bf16 3-term, register-streamed B) ---------
// grid (8 = 2 th x 4 hs, 64 b), 256 thr. Block: 128t x 128e, 2 h-chunks of 32.
// Waves: 2tg x 2eg, each 64t x 64e (mi=4, ni=4) -> half the A-LDS reads/MFMA.
#define C2_ROWS 384
__global__ __launch_bounds__(256, 2) void conv2_mfma(
    const float* __restrict__ hf, const unsigned int* __restrict__ wp2u,
    const float* __restrict__ bn, float* __restrict__ z) {
  __shared__ __align__(16) unsigned short Alds[C2_ROWS * 64];   // 49152 B
  const int th = blockIdx.x & 1, hs = blockIdx.x >> 1, b = blockIdx.y;
  const int tid = threadIdx.x, lane = tid & 63, wv = tid >> 6;
  const int quad = lane >> 4, l15 = lane & 15;
  const int tg = wv & 1, eg = wv >> 1;
  unsigned int* Au = (unsigned int*)Alds;

#define LOADB2(buf, KK, HG) do {                                                  \
    const uint4* _b = (const uint4*)(wp2u + (size_t)(KK) * 32768u +               \
                                     (size_t)(HG) * 4096u) + (eg * 4) * 128;      \
    buf[0] = _b[lane];        buf[1] = _b[64 + lane];                             \
    buf[2] = _b[128 + lane];  buf[3] = _b[192 + lane];                            \
    buf[4] = _b[256 + lane];  buf[5] = _b[320 + lane];                            \
    buf[6] = _b[384 + lane];  buf[7] = _b[448 + lane];                            \
  } while (0)

#define MSTEP2(KK, buf) do {                                                      \
    short8 bh0 = as_s8(buf[0]), bl0 = as_s8(buf[1]);                              \
    short8 bh1 = as_s8(buf[2]), bl1 = as_s8(buf[3]);                              \
    short8 bh2 = as_s8(buf[4]), bl2 = as_s8(buf[5]);                              \
    short8 bh3 = as_s8(buf[6]), bl3 = as_s8(buf[7]);                              \
    _Pragma("unroll")                                                             \
    for (int mi = 0; mi < 4; ++mi) {                                              \
      const int row = tg * 64 + mi * 16 + l15 + (KK);                             \
      const int sw = row & 7;                                                     \
      short8 ah = *(const short8*)&Alds[row * 64 + ((quad ^ sw) << 3)];           \
      short8 al = *(const short8*)&Alds[row * 64 + (((quad ^ 4) ^ sw) << 3)];     \
      acc[mi][0] = __builtin_amdgcn_mfma_f32_16x16x32_bf16(ah, bh0, acc[mi][0], 0, 0, 0); \
      acc[mi][0] = __builtin_amdgcn_mfma_f32_16x16x32_bf16(ah, bl0, acc[mi][0], 0, 0, 0); \
      acc[mi][0] = __builtin_amdgcn_mfma_f32_16x16x32_bf16(al, bh0, acc[mi][0], 0, 0, 0); \
      acc[mi][1] = __builtin_amdgcn_mfma_f32_16x16x32_bf16(ah, bh1, acc[mi][1], 0, 0, 0); \
      acc[mi][1] = __builtin_amdgcn_mfma_f32_16x16x32_bf16(ah, bl1, acc[mi][1], 0, 0, 0); \
      acc[mi][1] = __builtin_amdgcn_mfma_f32_16x16x32_bf16(al, bh1, acc[mi][1], 0, 0, 0); \
      acc[mi][2] = __builtin_amdgcn_mfma_f32_16x16x32_bf16(ah, bh2, acc[mi][2], 0, 0, 0); \
      acc[mi][2] = __builtin_amdgcn_mfma_f32_16x16x32_bf16(ah, bl2, acc[mi][2], 0, 0, 0); \
      acc[mi][2] = __builtin_amdgcn_mfma_f32_16x16x32_bf16(al, bh2, acc[mi][2], 0, 0, 0); \
      acc[mi][3] = __builtin_amdgcn_mfma_f32_16x16x32_bf16(ah, bh3, acc[mi][3], 0, 0, 0); \
      acc[mi][3] = __builtin_amdgcn_mfma_f32_16x16x32_bf16(ah, bl3, acc[mi][3], 0, 0, 0); \
      acc[mi][3] = __builtin_amdgcn_mfma_f32_16x16x32_bf16(al, bh3, acc[mi][3], 0, 0, 0); \
    }                                                                             \
  } while (0)

  float4v acc[4][4];
#pragma unroll
  for (int mi = 0; mi < 4; ++mi)
#pragma unroll
    for (int ni = 0; ni < 4; ++ni) acc[mi][ni] = (float4v)(0.f);

  uint4 b0[8], b1x[8];

  for (int hc = 0; hc < 2; ++hc) {
    const int hcg = hs * 2 + hc;
    __syncthreads();   // all reads of Alds from previous chunk done
    for (int idx = tid; idx < C2_ROWS * 16; idx += 256) {
      int r = idx >> 4, p = idx & 15;
      int t = th * 128 + r - NPAD;
      float v0 = 0.f, v1 = 0.f;
      int h0c = hcg * 32 + p * 2;
      if (t >= 0 && t < TT) {
        const float* hp = &hf[(size_t)(b * 256 + t) * NH + h0c];
        v0 = hp[0] * bn[512 + h0c] + bn[768 + h0c];
        v1 = hp[1] * bn[512 + h0c + 1] + bn[768 + h0c + 1];
      }
      unsigned short h0 = f2bf(v0), h1 = f2bf(v1);
      unsigned short l0 = f2bf(v0 - bf2f(h0)), l1 = f2bf(v1 - bf2f(h1));
      int sw = r & 7;
      Au[r * 32 + ((((p >> 2) ^ sw) << 2) | (p & 3))] = (unsigned int)h0 | ((unsigned int)h1 << 16);
      Au[r * 32 + (((((p >> 2) + 4) ^ sw) << 2) | (p & 3))] = (unsigned int)l0 | ((unsigned int)l1 << 16);
    }
    if (hc == 0) LOADB2(b0, 0, hcg);
    __syncthreads();

    for (int kp = 0; kp < 127; ++kp) {
      const int kk = kp * 2;
      LOADB2(b1x, kk + 1, hcg);
      MSTEP2(kk, b0);
      LOADB2(b0, kk + 2, hcg);
      MSTEP2(kk + 1, b1x);
    }
    MSTEP2(254, b0);
    if (hc == 0) LOADB2(b0, 0, hcg + 1);   // cross-chunk prefetch
  }

#pragma unroll
  for (int mi = 0; mi < 4; ++mi) {
#pragma unroll
    for (int ni = 0; ni < 4; ++ni) {
      int e = (eg * 4 + ni) * 16 + l15;
#pragma unroll
      for (int r = 0; r < 4; ++r) {
        int t = th * 128 + tg * 64 + mi * 16 + quad * 4 + r;
        if (t < TT) atomicAdd(&z[(size_t)(b * NE + e) * TT + t], acc[mi][ni][r]);
      }
    }
  }
#undef LOADB2
#undef MSTEP2
}

// ---------------- MLP layer 1 (fp32) ----------------
__global__ __launch_bounds__(256) void mlp1_k(const float* __restrict__ z,
                                              const float* __restrict__ pw1,
                                              const float* __restrict__ pb1,
                                              float* __restrict__ hmid) {
  const int TC = 128;
  __shared__ float zl[TC * 68];
  __shared__ float pl[TC * 68];
  const int c = blockIdx.y, h0 = blockIdx.x * 64, tid = threadIdx.x;
  const int h4 = tid & 15, b4 = tid >> 4;
  float acc[4][4];
#pragma unroll
  for (int a = 0; a < 4; ++a)
#pragma unroll
    for (int bb = 0; bb < 4; ++bb) acc[a][bb] = 0.f;
  for (int t0 = 0; t0 < TT; t0 += TC) {
    const int tc = min(TC, TT - t0);
    __syncthreads();
    for (int idx = tid; idx < 64 * tc; idx += 256) {
      int r = idx / tc, t = idx - r * tc;
      zl[t * 68 + r] = z[(size_t)(r * NE + c) * TT + t0 + t];
      pl[t * 68 + r] = pw1[(size_t)(c * NH + h0 + r) * TT + t0 + t];
    }
    __syncthreads();
    for (int t = 0; t < tc; ++t) {
      float4 zv = *(const float4*)&zl[t * 68 + b4 * 4];
      float4 pv = *(const float4*)&pl[t * 68 + h4 * 4];
      float zz[4] = {zv.x, zv.y, zv.z, zv.w};
      float pp[4] = {pv.x, pv.y, pv.z, pv.w};
#pragma unroll
      for (int a = 0; a < 4; ++a)
#pragma unroll
        for (int bb = 0; bb < 4; ++bb) acc[a][bb] = fmaf(pp[a], zz[bb], acc[a][bb]);
    }
  }
#pragma unroll
  for (int a = 0; a < 4; ++a) {
    int hh = h0 + h4 * 4 + a;
    float bias = pb1[c * NH + hh];
#pragma unroll
    for (int bb = 0; bb < 4; ++bb) {
      int bidx = b4 * 4 + bb;
      float v = acc[a][bb] + bias;
      hmid[(size_t)(bidx * NE + c) * NH + hh] = fmaxf(v, 0.f);
    }
  }
}

// ---------------- MLP layer 2 + atan2 ----------------
__global__ __launch_bounds__(256) void mlp2_k(const float* __restrict__ hmid,
                                              const float* __restrict__ pw2,
                                              const float* __restrict__ pb2,
                                              float* __restrict__ out) {
  const int tid = threadIdx.x, lane = tid & 63, wv = tid >> 6;
  const int p = blockIdx.x * 4 + wv;
  const int b = p >> 7, c = p & 127;
  const float4 hv = *(const float4*)&hmid[(size_t)(b * NE + c) * NH + lane * 4];
  const float4 p0 = *(const float4*)&pw2[(size_t)(c * 2 + 0) * NH + lane * 4];
  const float4 p1 = *(const float4*)&pw2[(size_t)(c * 2 + 1) * NH + lane * 4];
  float s0 = hv.x * p0.x + hv.y * p0.y + hv.z * p0.z + hv.w * p0.w;
  float s1 = hv.x * p1.x + hv.y * p1.y + hv.z * p1.z + hv.w * p1.w;
#pragma unroll
  for (int off = 32; off; off >>= 1) {
    s0 += __shfl_down(s0, off);
    s1 += __shfl_down(s1, off);
  }
  if (lane == 0) {
    float a0 = s0 + pb2[c * 2 + 0];
    float a1 = s1 + pb2[c * 2 + 1];
    out[O_PHASE + b * NE + c] = atan2f(a1, a0);
  }
}

// ---------------- amplitude (Parseval) + constant frequency ----------------
__global__ __launch_bounds__(256) void amp_k(const float* __restrict__ z,
                                             float* __restrict__ out) {
  const int tid = threadIdx.x, lane = tid & 63, wv = tid >> 6;
  const int b = blockIdx.x, c = blockIdx.y * 4 + wv;
  const float* row = z + (size_t)(b * NE + c) * TT;
  float s1 = 0.f, s2 = 0.f;
  for (int idx = lane; idx < TT; idx += 64) {
    float v = row[idx];
    s1 += v; s2 += v * v;
  }
#pragma unroll
  for (int off = 32; off; off >>= 1) {
    s1 += __shfl_down(s1, off);
    s2 += __shfl_down(s2, off);
  }
  if (lane == 0 && c >= 1) {
    float P = 0.5f * (255.f * s2 + s1 * s1);
    out[O_AMP + b * 127 + (c - 1)] = 2.f * sqrtf(P) / 255.f;
    out[O_FREQ + b * 127 + (c - 1)] = (float)c / 255.f;
  }
}

// ---------------- offset: real rfft spectrum of channel 0 ----------------
__global__ __launch_bounds__(128) void offset_k(const float* __restrict__ z,
                                                float* __restrict__ out) {
  __shared__ float zr[TT];
  __shared__ float ct[TT];
  const int b = blockIdx.x, tid = threadIdx.x;
  for (int idx = tid; idx < TT; idx += 128) {
    zr[idx] = z[(size_t)(b * NE + 0) * TT + idx];
    ct[idx] = cosf(6.283185307179586f * (float)idx / 255.f);
  }
  __syncthreads();
  const int f = tid;
  float s = 0.f;
  int m = 0;
  for (int t = 0; t < TT; ++t) {
    s += zr[t] * ct[m];
    m += f; if (m >= TT) m -= TT;
  }
  out[O_OFF + b * NE + f] = s / 255.f;
}

extern "C" void kernel_launch(void* const* d_in, const int* in_sizes, int n_in,
                              void* d_out, int out_size, void* d_ws, size_t ws_size,
                              hipStream_t stream) {
  (void)in_sizes; (void)n_in; (void)out_size; (void)ws_size;
  const float* s       = (const float*)d_in[0];
  const float* conv1_w = (const float*)d_in[1];
  const float* conv1_b = (const float*)d_in[2];
  const float* bn_g    = (const float*)d_in[3];
  const float* bn_b    = (const float*)d_in[4];
  const float* conv2_w = (const float*)d_in[5];
  const float* conv2_b = (const float*)d_in[6];
  const float* pw1     = (const float*)d_in[7];
  const float* pb1     = (const float*)d_in[8];
  const float* pw2     = (const float*)d_in[9];
  const float* pb2     = (const float*)d_in[10];
  float* out = (float*)d_out;
  char* ws   = (char*)d_ws;

  unsigned int* wp1u = (unsigned int*)(ws + WSB_WP1);
  unsigned int* wp2u = (unsigned int*)(ws + WSB_WP2);
  float* hf   = (float*)(ws + WSB_H);
  float* z    = (float*)(ws + WSB_Z);      // aliases wp1 (dead after conv1)
  float* bn   = (float*)(ws + WSB_BN);
  float* hmid = (float*)(ws + WSB_HMID);   // aliases hf (dead after conv2)

  bn_zero_k<<<1, 256, 0, stream>>>(bn);
  pack1_k<<<dim3(16, 8), 256, 0, stream>>>(conv1_w, wp1u);
  pack2_k<<<dim3(64, 8), 256, 0, stream>>>(conv2_w, wp2u);

  conv1_mfma<<<dim3(8, TB), 256, 0, stream>>>(s, wp1u, conv1_b, hf, bn);
  bn_final_k<<<1, 256, 0, stream>>>(bn_g, bn_b, bn);

  z_init_k<<<2040, 1024, 0, stream>>>(conv2_b, z);   // overwrites wp1 region
  conv2_mfma<<<dim3(8, TB), 256, 0, stream>>>(hf, wp2u, bn, z);

  mlp1_k<<<dim3(4, NE), 256, 0, stream>>>(z, pw1, pb1, hmid);
  mlp2_k<<<TB * NE / 4, 256, 0, stream>>>(hmid, pw2, pb2, out);
  amp_k<<<dim3(TB, 32), 256, 0, stream>>>(z, out);
  offset_k<<<TB, 128, 0, stream>>>(z, out);
}

// Round 8
// 1008.393 us; speedup vs baseline: 1.3922x; 1.0200x over previous
//
#include <hip/hip_runtime.h>
#include <math.h>

#define TB   64
#define TT   255
#define TIN  32
#define NH   256
#define NE   128
#define NK   255
#define NPAD 127

typedef __attribute__((ext_vector_type(8))) short short8;
typedef __attribute__((ext_vector_type(4))) float float4v;

// ---- workspace layout (byte offsets) ----
#define WSB_WP1  0u
#define WSB_Z    0u
#define WSB_WP2  8388608u
#define WSB_H    41811968u
#define WSB_HMID 41811968u
#define WSB_BN   58589184u   // 4 x 256 f32: sum1/sum2/sc/sh

// ---- output layout (float offsets) ----
#define O_AMP   0u
#define O_PHASE 8128u
#define O_FREQ  16320u
#define O_OFF   24448u

static __device__ __forceinline__ unsigned short f2bf(float f) {
  unsigned int u = __float_as_uint(f);
  unsigned int r = (u + 0x7FFFu + ((u >> 16) & 1u)) >> 16;
  return (unsigned short)r;
}
static __device__ __forceinline__ float bf2f(unsigned short s) {
  return __uint_as_float(((unsigned int)s) << 16);
}
static __device__ __forceinline__ short8 as_s8(uint4 v) {
  union { uint4 u; short8 s; } c; c.u = v; return c.s;
}

// ---------------- small init kernels ----------------
__global__ __launch_bounds__(256) void bn_zero_k(float* __restrict__ bn) {
  bn[threadIdx.x] = 0.f;
  bn[256 + threadIdx.x] = 0.f;
}

__global__ __launch_bounds__(1024) void z_init_k(const float* __restrict__ b2,
                                                 float* __restrict__ z) {
  int idx = blockIdx.x * 1024 + threadIdx.x;   // 2040*1024 == 64*128*255
  int e = (idx / TT) % NE;
  z[idx] = b2[e];
}

// ---------------- weight packing (hi/lo split) ----------------
// wp1[kk][et(16)][p(2)][lane][j]: split_p( w1[e=et*16+(lane&15)][i=(lane>>4)*8+j][kk] )
__global__ __launch_bounds__(256) void pack1_k(const float* __restrict__ w1,
                                               unsigned int* __restrict__ wp1u) {
  __shared__ float tile[512][33];
  const int et = blockIdx.x, kc = blockIdx.y;
  const int kk0 = kc * 32, cnt = min(32, NK - kk0);
  const int tid = threadIdx.x;
  for (int idx = tid; idx < 512 * 32; idx += 256) {
    int row = idx >> 5, kl = idx & 31;
    if (kl < cnt) {
      int e_l = row >> 5, i_l = row & 31;
      tile[row][kl] = w1[(size_t)((et * 16 + e_l) * TIN + i_l) * NK + kk0 + kl];
    }
  }
  __syncthreads();
  const int lane = tid >> 2, jp = (tid & 3) * 2;
  const int row0 = (lane & 15) * 32 + (lane >> 4) * 8 + jp;
  for (int kl = 0; kl < cnt; ++kl) {
    float w0 = tile[row0][kl], w1v = tile[row0 + 1][kl];
    unsigned short h0 = f2bf(w0), h1 = f2bf(w1v);
    unsigned short l0 = f2bf(w0 - bf2f(h0)), l1 = f2bf(w1v - bf2f(h1));
    size_t base = (size_t)(kk0 + kl) * 8192 + et * 512 + tid;
    wp1u[base] = (unsigned int)h0 | ((unsigned int)h1 << 16);
    wp1u[base + 256] = (unsigned int)l0 | ((unsigned int)l1 << 16);
  }
}

// wp2[kk][hcg(8)][et(8)][p(2)][lane][j]: split_p( w2[e=et*16+(lane&15)][h=hcg*32+(lane>>4)*8+j][kk] )
__global__ __launch_bounds__(256) void pack2_k(const float* __restrict__ w2,
                                               unsigned int* __restrict__ wp2u) {
  __shared__ float tile[512][33];
  const int hcg = blockIdx.x >> 3, et = blockIdx.x & 7, kc = blockIdx.y;
  const int kk0 = kc * 32, cnt = min(32, NK - kk0);
  const int tid = threadIdx.x;
  for (int idx = tid; idx < 512 * 32; idx += 256) {
    int row = idx >> 5, kl = idx & 31;
    if (kl < cnt) {
      int e_l = row >> 5, h_l = row & 31;
      tile[row][kl] = w2[(size_t)((et * 16 + e_l) * NH + hcg * 32 + h_l) * NK + kk0 + kl];
    }
  }
  __syncthreads();
  const int lane = tid >> 2, jp = (tid & 3) * 2;
  const int row0 = (lane & 15) * 32 + (lane >> 4) * 8 + jp;
  for (int kl = 0; kl < cnt; ++kl) {
    float w0 = tile[row0][kl], w1v = tile[row0 + 1][kl];
    unsigned short h0 = f2bf(w0), h1 = f2bf(w1v);
    unsigned short l0 = f2bf(w0 - bf2f(h0)), l1 = f2bf(w1v - bf2f(h1));
    size_t base = (size_t)(kk0 + kl) * 32768 + hcg * 4096 + et * 512 + tid;
    wp2u[base] = (unsigned int)h0 | ((unsigned int)h1 << 16);
    wp2u[base + 256] = (unsigned int)l0 | ((unsigned int)l1 << 16);
  }
}

// ---------------- conv1 MFMA (split-bf16 3-term, depth-3 B ring) --------------
// grid (8 = 2 th x 4 chg, 64 b), 256 thr. Block: 128t x 64ch.
// Waves: 2tg x 2eg, each 64t x 32ch (mi=4, ni=2). LDS 48 KB. Fused BN stats.
#define C1_ROWS 384
__global__ __launch_bounds__(256, 2) void conv1_mfma(
    const float* __restrict__ s, const unsigned int* __restrict__ wp1u,
    const float* __restrict__ b1v, float* __restrict__ hf, float* __restrict__ bn) {
  __shared__ __align__(16) unsigned short Alds[C1_ROWS * 64];   // 49152 B
  const int th = blockIdx.x & 1, chg = blockIdx.x >> 1, b = blockIdx.y;
  const int tid = threadIdx.x, lane = tid & 63, wv = tid >> 6;
  const int quad = lane >> 4, l15 = lane & 15;
  const int tg = wv & 1, eg = wv >> 1;
  unsigned int* Au = (unsigned int*)Alds;

  for (int idx = tid; idx < C1_ROWS * 16; idx += 256) {
    int r = idx >> 4, p = idx & 15;
    int t = th * 128 + r - NPAD;
    float v0 = 0.f, v1 = 0.f;
    if (t >= 0 && t < TT) {
      const float* sp = &s[(size_t)(b * TT + t) * TIN + p * 2];
      v0 = sp[0]; v1 = sp[1];
    }
    unsigned short h0 = f2bf(v0), h1 = f2bf(v1);
    unsigned short l0 = f2bf(v0 - bf2f(h0)), l1 = f2bf(v1 - bf2f(h1));
    int sw = r & 7;
    Au[r * 32 + ((((p >> 2) ^ sw) << 2) | (p & 3))] = (unsigned int)h0 | ((unsigned int)h1 << 16);
    Au[r * 32 + (((((p >> 2) + 4) ^ sw) << 2) | (p & 3))] = (unsigned int)l0 | ((unsigned int)l1 << 16);
  }

#define LOADB1(buf, KK) do {                                                      \
    const uint4* _b = (const uint4*)(wp1u + (size_t)(KK) * 8192u) +               \
                      (chg * 4 + eg * 2) * 128;                                   \
    buf[0] = _b[lane];          buf[1] = _b[64 + lane];                           \
    buf[2] = _b[128 + lane];    buf[3] = _b[192 + lane];                          \
  } while (0)

#define MSTEP1(KK, buf) do {                                                      \
    short8 bh0 = as_s8(buf[0]), bl0 = as_s8(buf[1]);                              \
    short8 bh1 = as_s8(buf[2]), bl1 = as_s8(buf[3]);                              \
    _Pragma("unroll")                                                             \
    for (int mi = 0; mi < 4; ++mi) {                                              \
      const int row = tg * 64 + mi * 16 + l15 + (KK);                             \
      const int sw = row & 7;                                                     \
      short8 ah = *(const short8*)&Alds[row * 64 + ((quad ^ sw) << 3)];           \
      short8 al = *(const short8*)&Alds[row * 64 + (((quad ^ 4) ^ sw) << 3)];     \
      acc[mi][0] = __builtin_amdgcn_mfma_f32_16x16x32_bf16(ah, bh0, acc[mi][0], 0, 0, 0); \
      acc[mi][0] = __builtin_amdgcn_mfma_f32_16x16x32_bf16(ah, bl0, acc[mi][0], 0, 0, 0); \
      acc[mi][0] = __builtin_amdgcn_mfma_f32_16x16x32_bf16(al, bh0, acc[mi][0], 0, 0, 0); \
      acc[mi][1] = __builtin_amdgcn_mfma_f32_16x16x32_bf16(ah, bh1, acc[mi][1], 0, 0, 0); \
      acc[mi][1] = __builtin_amdgcn_mfma_f32_16x16x32_bf16(ah, bl1, acc[mi][1], 0, 0, 0); \
      acc[mi][1] = __builtin_amdgcn_mfma_f32_16x16x32_bf16(al, bh1, acc[mi][1], 0, 0, 0); \
    }                                                                             \
  } while (0)

  uint4 b0[4], b1x[4], b2x[4];
  LOADB1(b0, 0);
  LOADB1(b1x, 1);
  LOADB1(b2x, 2);
  __syncthreads();

  float4v acc[4][2];
#pragma unroll
  for (int mi = 0; mi < 4; ++mi)
#pragma unroll
    for (int ni = 0; ni < 2; ++ni) acc[mi][ni] = (float4v)(0.f);

  for (int kp = 0; kp < 84; ++kp) {
    const int kk = kp * 3;
    MSTEP1(kk, b0);     LOADB1(b0, kk + 3);
    MSTEP1(kk + 1, b1x); LOADB1(b1x, kk + 4);
    MSTEP1(kk + 2, b2x); LOADB1(b2x, kk + 5);
  }
  MSTEP1(252, b0);
  MSTEP1(253, b1x);
  MSTEP1(254, b2x);

  // epilogue + fused BN partial sums
  float s1[2] = {0.f, 0.f}, s2[2] = {0.f, 0.f};
#pragma unroll
  for (int mi = 0; mi < 4; ++mi) {
#pragma unroll
    for (int ni = 0; ni < 2; ++ni) {
      int ch = chg * 64 + (eg * 2 + ni) * 16 + l15;
      float bias = b1v[ch];
#pragma unroll
      for (int r = 0; r < 4; ++r) {
        int t = th * 128 + tg * 64 + mi * 16 + quad * 4 + r;
        if (t < TT) {
          float v = fmaxf(acc[mi][ni][r] + bias, 0.f);
          hf[(size_t)(b * 256 + t) * NH + ch] = v;
          s1[ni] += v; s2[ni] += v * v;
        }
      }
    }
  }
#pragma unroll
  for (int ni = 0; ni < 2; ++ni) {
    s1[ni] += __shfl_xor(s1[ni], 16);
    s1[ni] += __shfl_xor(s1[ni], 32);
    s2[ni] += __shfl_xor(s2[ni], 16);
    s2[ni] += __shfl_xor(s2[ni], 32);
    if (quad == 0) {
      int ch = chg * 64 + (eg * 2 + ni) * 16 + l15;
      atomicAdd(&bn[ch], s1[ni]);
      atomicAdd(&bn[256 + ch], s2[ni]);
    }
  }
#undef LOADB1
#undef MSTEP1
}

__global__ __launch_bounds__(256) void bn_final_k(const float* __restrict__ gamma,
                                                  const float* __restrict__ beta,
                                                  float* __restrict__ bn) {
  const int h = threadIdx.x;
  const float inv = 1.0f / (TB * TT);
  float m = bn[h] * inv;
  float var = bn[256 + h] * inv - m * m;
  float sc = gamma[h] / sqrtf(var + 1e-5f);
  bn[512 + h] = sc;
  bn[768 + h] = beta[h] - m * sc;
}

// ---------------- conv2 MFMA (split-bf16 3-term, depth-3 B ring, e-split) -----
// grid (16 = 2 es x 2 th x 4 hs, 64 b), 256 thr. Block: 128t x 64e, 2 h-chunks.
// Waves: 2tg x 2eg, each 64t x 32e (mi=4, ni=2). LDS 48 KB -> 3 blocks/CU.
#define C2_ROWS 384
__global__ __launch_bounds__(256, 3) void conv2_mfma(
    const float* __restrict__ hf, const unsigned int* __restrict__ wp2u,
    const float* __restrict__ bn, float* __restrict__ z) {
  __shared__ __align__(16) unsigned short Alds[C2_ROWS * 64];   // 49152 B
  const int es = blockIdx.x & 1, th = (blockIdx.x >> 1) & 1, hs = blockIdx.x >> 2;
  const int b = blockIdx.y;
  const int tid = threadIdx.x, lane = tid & 63, wv = tid >> 6;
  const int quad = lane >> 4, l15 = lane & 15;
  const int tg = wv & 1, eg = wv >> 1;
  unsigned int* Au = (unsigned int*)Alds;

#define LOADB2(buf, KK, HG) do {                                                  \
    const uint4* _b = (const uint4*)(wp2u + (size_t)(KK) * 32768u +               \
                                     (size_t)(HG) * 4096u) +                      \
                      (es * 4 + eg * 2) * 128;                                    \
    buf[0] = _b[lane];        buf[1] = _b[64 + lane];                             \
    buf[2] = _b[128 + lane];  buf[3] = _b[192 + lane];                            \
  } while (0)

#define MSTEP2(KK, buf) do {                                                      \
    short8 bh0 = as_s8(buf[0]), bl0 = as_s8(buf[1]);                              \
    short8 bh1 = as_s8(buf[2]), bl1 = as_s8(buf[3]);                              \
    _Pragma("unroll")                                                             \
    for (int mi = 0; mi < 4; ++mi) {                                              \
      const int row = tg * 64 + mi * 16 + l15 + (KK);                             \
      const int sw = row & 7;                                                     \
      short8 ah = *(const short8*)&Alds[row * 64 + ((quad ^ sw) << 3)];           \
      short8 al = *(const short8*)&Alds[row * 64 + (((quad ^ 4) ^ sw) << 3)];     \
      acc[mi][0] = __builtin_amdgcn_mfma_f32_16x16x32_bf16(ah, bh0, acc[mi][0], 0, 0, 0); \
      acc[mi][0] = __builtin_amdgcn_mfma_f32_16x16x32_bf16(ah, bl0, acc[mi][0], 0, 0, 0); \
      acc[mi][0] = __builtin_amdgcn_mfma_f32_16x16x32_bf16(al, bh0, acc[mi][0], 0, 0, 0); \
      acc[mi][1] = __builtin_amdgcn_mfma_f32_16x16x32_bf16(ah, bh1, acc[mi][1], 0, 0, 0); \
      acc[mi][1] = __builtin_amdgcn_mfma_f32_16x16x32_bf16(ah, bl1, acc[mi][1], 0, 0, 0); \
      acc[mi][1] = __builtin_amdgcn_mfma_f32_16x16x32_bf16(al, bh1, acc[mi][1], 0, 0, 0); \
    }                                                                             \
  } while (0)

  float4v acc[4][2];
#pragma unroll
  for (int mi = 0; mi < 4; ++mi)
#pragma unroll
    for (int ni = 0; ni < 2; ++ni) acc[mi][ni] = (float4v)(0.f);

  uint4 b0[4], b1x[4], b2x[4];

  for (int hc = 0; hc < 2; ++hc) {
    const int hcg = hs * 2 + hc;
    __syncthreads();   // all reads of Alds from previous chunk done
    for (int idx = tid; idx < C2_ROWS * 16; idx += 256) {
      int r = idx >> 4, p = idx & 15;
      int t = th * 128 + r - NPAD;
      float v0 = 0.f, v1 = 0.f;
      int h0c = hcg * 32 + p * 2;
      if (t >= 0 && t < TT) {
        const float* hp = &hf[(size_t)(b * 256 + t) * NH + h0c];
        v0 = hp[0] * bn[512 + h0c] + bn[768 + h0c];
        v1 = hp[1] * bn[512 + h0c + 1] + bn[768 + h0c + 1];
      }
      unsigned short h0 = f2bf(v0), h1 = f2bf(v1);
      unsigned short l0 = f2bf(v0 - bf2f(h0)), l1 = f2bf(v1 - bf2f(h1));
      int sw = r & 7;
      Au[r * 32 + ((((p >> 2) ^ sw) << 2) | (p & 3))] = (unsigned int)h0 | ((unsigned int)h1 << 16);
      Au[r * 32 + (((((p >> 2) + 4) ^ sw) << 2) | (p & 3))] = (unsigned int)l0 | ((unsigned int)l1 << 16);
    }
    if (hc == 0) {
      LOADB2(b0, 0, hcg);
      LOADB2(b1x, 1, hcg);
      LOADB2(b2x, 2, hcg);
    }
    __syncthreads();

    for (int kp = 0; kp < 84; ++kp) {
      const int kk = kp * 3;
      MSTEP2(kk, b0);      LOADB2(b0, kk + 3, hcg);
      MSTEP2(kk + 1, b1x); LOADB2(b1x, kk + 4, hcg);
      MSTEP2(kk + 2, b2x); LOADB2(b2x, kk + 5, hcg);
    }
    MSTEP2(252, b0);
    if (hc == 0) LOADB2(b0, 0, hcg + 1);
    MSTEP2(253, b1x);
    if (hc == 0) LOADB2(b1x, 1, hcg + 1);
    MSTEP2(254, b2x);
    if (hc == 0) LOADB2(b2x, 2, hcg + 1);
  }

#pragma unroll
  for (int mi = 0; mi < 4; ++mi) {
#pragma unroll
    for (int ni = 0; ni < 2; ++ni) {
      int e = es * 64 + eg * 32 + ni * 16 + l15;
#pragma unroll
      for (int r = 0; r < 4; ++r) {
        int t = th * 128 + tg * 64 + mi * 16 + quad * 4 + r;
        if (t < TT) atomicAdd(&z[(size_t)(b * NE + e) * TT + t], acc[mi][ni][r]);
      }
    }
  }
#undef LOADB2
#undef MSTEP2
}

// ---------------- MLP layer 1 (fp32) ----------------
__global__ __launch_bounds__(256) void mlp1_k(const float* __restrict__ z,
                                              const float* __restrict__ pw1,
                                              const float* __restrict__ pb1,
                                              float* __restrict__ hmid) {
  const int TC = 128;
  __shared__ float zl[TC * 68];
  __shared__ float pl[TC * 68];
  const int c = blockIdx.y, h0 = blockIdx.x * 64, tid = threadIdx.x;
  const int h4 = tid & 15, b4 = tid >> 4;
  float acc[4][4];
#pragma unroll
  for (int a = 0; a < 4; ++a)
#pragma unroll
    for (int bb = 0; bb < 4; ++bb) acc[a][bb] = 0.f;
  for (int t0 = 0; t0 < TT; t0 += TC) {
    const int tc = min(TC, TT - t0);
    __syncthreads();
    for (int idx = tid; idx < 64 * tc; idx += 256) {
      int r = idx / tc, t = idx - r * tc;
      zl[t * 68 + r] = z[(size_t)(r * NE + c) * TT + t0 + t];
      pl[t * 68 + r] = pw1[(size_t)(c * NH + h0 + r) * TT + t0 + t];
    }
    __syncthreads();
    for (int t = 0; t < tc; ++t) {
      float4 zv = *(const float4*)&zl[t * 68 + b4 * 4];
      float4 pv = *(const float4*)&pl[t * 68 + h4 * 4];
      float zz[4] = {zv.x, zv.y, zv.z, zv.w};
      float pp[4] = {pv.x, pv.y, pv.z, pv.w};
#pragma unroll
      for (int a = 0; a < 4; ++a)
#pragma unroll
        for (int bb = 0; bb < 4; ++bb) acc[a][bb] = fmaf(pp[a], zz[bb], acc[a][bb]);
    }
  }
#pragma unroll
  for (int a = 0; a < 4; ++a) {
    int hh = h0 + h4 * 4 + a;
    float bias = pb1[c * NH + hh];
#pragma unroll
    for (int bb = 0; bb < 4; ++bb) {
      int bidx = b4 * 4 + bb;
      float v = acc[a][bb] + bias;
      hmid[(size_t)(bidx * NE + c) * NH + hh] = fmaxf(v, 0.f);
    }
  }
}

// ---------------- MLP layer 2 + atan2 ----------------
__global__ __launch_bounds__(256) void mlp2_k(const float* __restrict__ hmid,
                                              const float* __restrict__ pw2,
                                              const float* __restrict__ pb2,
                                              float* __restrict__ out) {
  const int tid = threadIdx.x, lane = tid & 63, wv = tid >> 6;
  const int p = blockIdx.x * 4 + wv;
  const int b = p >> 7, c = p & 127;
  const float4 hv = *(const float4*)&hmid[(size_t)(b * NE + c) * NH + lane * 4];
  const float4 p0 = *(const float4*)&pw2[(size_t)(c * 2 + 0) * NH + lane * 4];
  const float4 p1 = *(const float4*)&pw2[(size_t)(c * 2 + 1) * NH + lane * 4];
  float s0 = hv.x * p0.x + hv.y * p0.y + hv.z * p0.z + hv.w * p0.w;
  float s1 = hv.x * p1.x + hv.y * p1.y + hv.z * p1.z + hv.w * p1.w;
#pragma unroll
  for (int off = 32; off; off >>= 1) {
    s0 += __shfl_down(s0, off);
    s1 += __shfl_down(s1, off);
  }
  if (lane == 0) {
    float a0 = s0 + pb2[c * 2 + 0];
    float a1 = s1 + pb2[c * 2 + 1];
    out[O_PHASE + b * NE + c] = atan2f(a1, a0);
  }
}

// ---------------- amplitude (Parseval) + constant frequency ----------------
__global__ __launch_bounds__(256) void amp_k(const float* __restrict__ z,
                                             float* __restrict__ out) {
  const int tid = threadIdx.x, lane = tid & 63, wv = tid >> 6;
  const int b = blockIdx.x, c = blockIdx.y * 4 + wv;
  const float* row = z + (size_t)(b * NE + c) * TT;
  float s1 = 0.f, s2 = 0.f;
  for (int idx = lane; idx < TT; idx += 64) {
    float v = row[idx];
    s1 += v; s2 += v * v;
  }
#pragma unroll
  for (int off = 32; off; off >>= 1) {
    s1 += __shfl_down(s1, off);
    s2 += __shfl_down(s2, off);
  }
  if (lane == 0 && c >= 1) {
    float P = 0.5f * (255.f * s2 + s1 * s1);
    out[O_AMP + b * 127 + (c - 1)] = 2.f * sqrtf(P) / 255.f;
    out[O_FREQ + b * 127 + (c - 1)] = (float)c / 255.f;
  }
}

// ---------------- offset: real rfft spectrum of channel 0 ----------------
__global__ __launch_bounds__(128) void offset_k(const float* __restrict__ z,
                                                float* __restrict__ out) {
  __shared__ float zr[TT];
  __shared__ float ct[TT];
  const int b = blockIdx.x, tid = threadIdx.x;
  for (int idx = tid; idx < TT; idx += 128) {
    zr[idx] = z[(size_t)(b * NE + 0) * TT + idx];
    ct[idx] = cosf(6.283185307179586f * (float)idx / 255.f);
  }
  __syncthreads();
  const int f = tid;
  float s = 0.f;
  int m = 0;
  for (int t = 0; t < TT; ++t) {
    s += zr[t] * ct[m];
    m += f; if (m >= TT) m -= TT;
  }
  out[O_OFF + b * NE + f] = s / 255.f;
}

extern "C" void kernel_launch(void* const* d_in, const int* in_sizes, int n_in,
                              void* d_out, int out_size, void* d_ws, size_t ws_size,
                              hipStream_t stream) {
  (void)in_sizes; (void)n_in; (void)out_size; (void)ws_size;
  const float* s       = (const float*)d_in[0];
  const float* conv1_w = (const float*)d_in[1];
  const float* conv1_b = (const float*)d_in[2];
  const float* bn_g    = (const float*)d_in[3];
  const float* bn_b    = (const float*)d_in[4];
  const float* conv2_w = (const float*)d_in[5];
  const float* conv2_b = (const float*)d_in[6];
  const float* pw1     = (const float*)d_in[7];
  const float* pb1     = (const float*)d_in[8];
  const float* pw2     = (const float*)d_in[9];
  const float* pb2     = (const float*)d_in[10];
  float* out = (float*)d_out;
  char* ws   = (char*)d_ws;

  unsigned int* wp1u = (unsigned int*)(ws + WSB_WP1);
  unsigned int* wp2u = (unsigned int*)(ws + WSB_WP2);
  float* hf   = (float*)(ws + WSB_H);
  float* z    = (float*)(ws + WSB_Z);      // aliases wp1 (dead after conv1)
  float* bn   = (float*)(ws + WSB_BN);
  float* hmid = (float*)(ws + WSB_HMID);   // aliases hf (dead after conv2)

  bn_zero_k<<<1, 256, 0, stream>>>(bn);
  pack1_k<<<dim3(16, 8), 256, 0, stream>>>(conv1_w, wp1u);
  pack2_k<<<dim3(64, 8), 256, 0, stream>>>(conv2_w, wp2u);

  conv1_mfma<<<dim3(8, TB), 256, 0, stream>>>(s, wp1u, conv1_b, hf, bn);
  bn_final_k<<<1, 256, 0, stream>>>(bn_g, bn_b, bn);

  z_init_k<<<2040, 1024, 0, stream>>>(conv2_b, z);   // overwrites wp1 region
  conv2_mfma<<<dim3(16, TB), 256, 0, stream>>>(hf, wp2u, bn, z);

  mlp1_k<<<dim3(4, NE), 256, 0, stream>>>(z, pw1, pb1, hmid);
  mlp2_k<<<TB * NE / 4, 256, 0, stream>>>(hmid, pw2, pb2, out);
  amp_k<<<dim3(TB, 32), 256, 0, stream>>>(z, out);
  offset_k<<<TB, 128, 0, stream>>>(z, out);
}